// Round 4
// baseline (739.277 us; speedup 1.0000x reference)
//
#include <hip/hip_runtime.h>
#include <math.h>

#define N_NODES 100000
#define N_EDGES 1600000
#define NEG_SLOPE 0.2f
#define EPS 1e-16f

__device__ __forceinline__ float lrelu(float v) { return v > 0.f ? v : NEG_SLOPE * v; }

// ---------------------------------------------------------------- zero deg
__global__ void k_zero_deg(int* __restrict__ deg) {
    int i = blockIdx.x * blockDim.x + threadIdx.x;
    if (i < N_NODES) deg[i] = 0;
}

// ---------------------------------------------------------------- histogram of dst
__global__ void k_hist(const int* __restrict__ ei, int* __restrict__ deg) {
    int e = blockIdx.x * blockDim.x + threadIdx.x;
    if (e < N_EDGES) atomicAdd(&deg[ei[N_EDGES + e]], 1);
}

// ---------------------------------------------------------------- scan level 1
__global__ void k_scan_part(const int* __restrict__ deg, int* __restrict__ loc,
                            int* __restrict__ partial) {
    __shared__ int tmp[256];
    int i = blockIdx.x * 256 + threadIdx.x;
    int v = (i < N_NODES) ? deg[i] : 0;
    tmp[threadIdx.x] = v;
    __syncthreads();
    for (int off = 1; off < 256; off <<= 1) {
        int t = (threadIdx.x >= off) ? tmp[threadIdx.x - off] : 0;
        __syncthreads();
        tmp[threadIdx.x] += t;
        __syncthreads();
    }
    if (i < N_NODES) loc[i] = tmp[threadIdx.x] - v;   // exclusive
    if (threadIdx.x == 255) partial[blockIdx.x] = tmp[255];
}

// ---------------------------------------------------------------- scan level 2 (nb <= 512)
__global__ void k_scan_tot(int* __restrict__ partial, int nb) {
    __shared__ int tmp[512];
    int v = (threadIdx.x < nb) ? partial[threadIdx.x] : 0;
    tmp[threadIdx.x] = v;
    __syncthreads();
    for (int off = 1; off < 512; off <<= 1) {
        int t = (threadIdx.x >= off) ? tmp[threadIdx.x - off] : 0;
        __syncthreads();
        tmp[threadIdx.x] += t;
        __syncthreads();
    }
    if (threadIdx.x < nb) partial[threadIdx.x] = tmp[threadIdx.x] - v;  // exclusive
}

// ---------------------------------------------------------------- scan level 3 + cursor init
__global__ void k_scan_add(const int* __restrict__ loc, const int* __restrict__ partial,
                           int* __restrict__ rowptr, int* __restrict__ cursor) {
    int i = blockIdx.x * blockDim.x + threadIdx.x;
    if (i < N_NODES) {
        int r = loc[i] + partial[i >> 8];
        rowptr[i] = r;
        cursor[i] = r;
    }
}

// ---------------------------------------------------------------- scatter edges into CSR slots (by dst)
__global__ void k_scatter(const int* __restrict__ ei, int* __restrict__ cursor,
                          int* __restrict__ csr_src) {
    int e = blockIdx.x * blockDim.x + threadIdx.x;
    if (e < N_EDGES) {
        int dst = ei[N_EDGES + e];
        int pos = atomicAdd(&cursor[dst], 1);
        csr_src[pos] = ei[e];
    }
}

// ---------------------------------------------------------------- K1: per-node layer-1 attention logits
__global__ void k_node1(const float* __restrict__ x, const float* __restrict__ w1,
                        const float* __restrict__ as1, const float* __restrict__ ad1,
                        float* __restrict__ a1s, float* __restrict__ a1d) {
    __shared__ float w1s[384];
    int tid = threadIdx.x;
    for (int i = tid; i < 384; i += 256) w1s[i] = w1[i];
    __syncthreads();
    int wave = tid >> 6, lane = tid & 63;
    int n = blockIdx.x * 4 + wave;
    if (n >= N_NODES) return;
    float x0 = x[n * 3 + 0], x1 = x[n * 3 + 1], x2 = x[n * 3 + 2];
    int j = lane, j2 = lane + 64;
    float ha = x0 * w1s[j * 3] + x1 * w1s[j * 3 + 1] + x2 * w1s[j * 3 + 2];
    float hb = x0 * w1s[j2 * 3] + x1 * w1s[j2 * 3 + 1] + x2 * w1s[j2 * 3 + 2];
    float p0s = ha * as1[j], p1s = hb * as1[j2];
    float p0d = ha * ad1[j], p1d = hb * ad1[j2];
    #pragma unroll
    for (int off = 16; off; off >>= 1) {
        p0s += __shfl_xor(p0s, off);
        p1s += __shfl_xor(p1s, off);
        p0d += __shfl_xor(p0d, off);
        p1d += __shfl_xor(p1d, off);
    }
    if ((lane & 31) == 0) {
        int h = lane >> 5;
        a1s[n * 4 + h] = p0s; a1s[n * 4 + 2 + h] = p1s;
        a1d[n * 4 + h] = p0d; a1d[n * 4 + 2 + h] = p1d;
    }
}

// ---------------------------------------------------------------- K-GAT1: layer-1 gather + finalize + ELU + w2 matvec + L2 logits
// 6250 blocks x 16 nodes (4 per wave): w2t staged once per block, 8 blocks/CU
#define GAT1_BLOCKS 6250
__global__ void k_gat1(const int* __restrict__ rowptr, const int* __restrict__ deg,
                       const int* __restrict__ csr_src,
                       const float* __restrict__ x, const float* __restrict__ w1,
                       const float* __restrict__ a1s, const float* __restrict__ a1d,
                       const float* __restrict__ b1, const float* __restrict__ w2,
                       const float* __restrict__ as2, const float* __restrict__ ad2,
                       float* __restrict__ h2, float* __restrict__ a2s, float* __restrict__ a2d) {
    __shared__ float w2t[128 * 33];   // [k][o], stride 33 -> conflict-free
    __shared__ float f1s[4][128];
    int tid = threadIdx.x;
    for (int i = tid; i < 4096; i += 256) {
        int o = i >> 7, k = i & 127;
        w2t[k * 33 + o] = w2[i];
    }
    __syncthreads();
    int wave = tid >> 6, lane = tid & 63;
    int j = lane, j2 = lane + 64;
    int h0 = j >> 5;                  // head of elem j; elem j2 head = 2+h0
    float wa0 = w1[j * 3], wa1 = w1[j * 3 + 1], wa2 = w1[j * 3 + 2];
    float wb0 = w1[j2 * 3], wb1 = w1[j2 * 3 + 1], wb2 = w1[j2 * 3 + 2];
    float b1j = b1[j], b1j2 = b1[j2];
    int o = lane & 31, half = lane >> 5;
    float as2o = as2[o], ad2o = ad2[o];
    int k0 = half * 64;
    const float* f = f1s[wave];

    int nbase = blockIdx.x * 16 + wave * 4;
    #pragma unroll 1
    for (int i = 0; i < 4; i++) {
        int n = nbase + i;
        if (n >= N_NODES) break;
        float adA = a1d[n * 4 + h0], adB = a1d[n * 4 + 2 + h0];
        int beg = rowptr[n], cnt = deg[n];
        float acc0 = 0.f, acc1 = 0.f, dA = 0.f, dB = 0.f;
        for (int t = 0; t < cnt; t++) {
            int s = csr_src[beg + t];
            float exA = __expf(lrelu(a1s[s * 4 + h0] + adA));
            float exB = __expf(lrelu(a1s[s * 4 + 2 + h0] + adB));
            float x0 = x[s * 3], x1 = x[s * 3 + 1], x2 = x[s * 3 + 2];
            float ha = x0 * wa0 + x1 * wa1 + x2 * wa2;
            float hb = x0 * wb0 + x1 * wb1 + x2 * wb2;
            acc0 += exA * ha; acc1 += exB * hb;
            dA += exA; dB += exB;
        }
        float v0 = acc0 / (dA + EPS) + b1j;
        float v1 = acc1 / (dB + EPS) + b1j2;
        f1s[wave][j]  = v0 > 0.f ? v0 : expm1f(v0);
        f1s[wave][j2] = v1 > 0.f ? v1 : expm1f(v1);
        // same-wave LDS write->read; compiler inserts lgkmcnt wait
        float acc = 0.f;
        #pragma unroll 8
        for (int t = 0; t < 64; t++)
            acc += f[k0 + t] * w2t[(k0 + t) * 33 + o];
        acc += __shfl_down(acc, 32);
        if (half == 0) {
            h2[n * 32 + o] = acc;
            float ps = acc * as2o, pd = acc * ad2o;
            #pragma unroll
            for (int off = 16; off; off >>= 1) {
                ps += __shfl_xor(ps, off);
                pd += __shfl_xor(pd, off);
            }
            if (o == 0) { a2s[n] = ps; a2d[n] = pd; }
        }
    }
}

// ---------------------------------------------------------------- K-GAT2: layer-2 gather + finalize (half-wave per node)
__global__ void k_gat2(const int* __restrict__ rowptr, const int* __restrict__ deg,
                       const int* __restrict__ csr_src,
                       const float* __restrict__ h2, const float* __restrict__ a2s,
                       const float* __restrict__ a2d, const float* __restrict__ b2,
                       float* __restrict__ hf) {
    int tid = threadIdx.x;
    int n = blockIdx.x * 8 + (tid >> 5);
    if (n >= N_NODES) return;
    int c = tid & 31;
    float ad = a2d[n];
    int beg = rowptr[n], cnt = deg[n];
    float acc = 0.f, den = 0.f;
    for (int t = 0; t < cnt; t++) {
        int s = csr_src[beg + t];
        float ex = __expf(lrelu(a2s[s] + ad));
        acc += ex * h2[s * 32 + c];
        den += ex;
    }
    hf[n * 32 + c] = acc / (den + EPS) + b2[c];
}

// ---------------------------------------------------------------- K-UV: per-node MLP factor u = A.hf, v = B.hf
// mw1 [32 x 64] = [A | B]; lanes 0-31 compute u row o, lanes 32-63 compute v row o
__global__ void k_uv(const float* __restrict__ hf, const float* __restrict__ mw1,
                     float* __restrict__ u, float* __restrict__ v) {
    int tid = threadIdx.x;
    int lane = tid & 63;
    int o = lane & 31, sel = lane >> 5;
    float w[32];
    const float4* wp = (const float4*)(mw1 + o * 64 + sel * 32);
    #pragma unroll
    for (int q = 0; q < 8; q++) {
        float4 t = wp[q];
        w[q * 4 + 0] = t.x; w[q * 4 + 1] = t.y; w[q * 4 + 2] = t.z; w[q * 4 + 3] = t.w;
    }
    float* dst = sel ? v : u;
    int wid = blockIdx.x * 4 + (tid >> 6);
    for (int n = wid; n < N_NODES; n += 1024 * 4) {
        float h = hf[n * 32 + o];      // both halves read the same 128B
        float acc = 0.f;
        #pragma unroll
        for (int k = 0; k < 32; k++)
            acc += w[k] * __shfl(h, k, 32);
        dst[n * 32 + o] = acc;
    }
}

// ---------------------------------------------------------------- K7: edge MLP = relu-sum of u[src]+v[dst] (8 edges/wave-pair)
__global__ void k_mlp(const int* __restrict__ ei, const float* __restrict__ u,
                      const float* __restrict__ v, const float* __restrict__ mb1,
                      const float* __restrict__ mw2, const float* __restrict__ mb2,
                      float* __restrict__ out) {
    int tid = threadIdx.x;
    int e = blockIdx.x * 8 + (tid >> 5);
    if (e >= N_EDGES) return;
    int c = tid & 31;
    int src = ei[e], dst = ei[N_EDGES + e];
    float t = u[src * 32 + c] + v[dst * 32 + c] + mb1[c];
    float s = fmaxf(t, 0.f) * mw2[c];
    #pragma unroll
    for (int off = 16; off; off >>= 1)
        s += __shfl_xor(s, off, 32);
    if (c == 0) out[e] = fmaxf(s + mb2[0], 0.f);
}

// ---------------------------------------------------------------- launch
extern "C" void kernel_launch(void* const* d_in, const int* in_sizes, int n_in,
                              void* d_out, int out_size, void* d_ws, size_t ws_size,
                              hipStream_t stream) {
    const float* x    = (const float*)d_in[0];
    const int*   ei   = (const int*)d_in[1];
    const float* w1   = (const float*)d_in[2];
    const float* as1  = (const float*)d_in[3];
    const float* ad1  = (const float*)d_in[4];
    const float* b1   = (const float*)d_in[5];
    const float* w2   = (const float*)d_in[6];
    const float* as2  = (const float*)d_in[7];
    const float* ad2  = (const float*)d_in[8];
    const float* b2   = (const float*)d_in[9];
    const float* mw1  = (const float*)d_in[10];
    const float* mb1  = (const float*)d_in[11];
    const float* mw2  = (const float*)d_in[12];
    const float* mb2  = (const float*)d_in[13];
    float* out = (float*)d_out;

    const int N = N_NODES, E = N_EDGES;
    int* deg     = (int*)d_ws;           // N
    int* rowptr  = deg + N;              // N
    int* cursor  = rowptr + N;           // N
    int* loc     = cursor + N;           // N
    int* partial = loc + N;              // 512
    int* csr_src = partial + 512;        // E
    float* a1s   = (float*)(csr_src + E);// 4N
    float* a1d   = a1s + 4 * N;          // 4N
    float* h2    = a1d + 4 * N;          // 32N
    float* a2s   = h2 + 32 * N;          // N
    float* a2d   = a2s + N;              // N
    float* hf    = a2d + N;              // 32N
    float* u     = hf + 32 * N;          // 32N
    float* v     = u + 32 * N;           // 32N

    const int nb = (N + 255) / 256;

    k_zero_deg<<<nb, 256, 0, stream>>>(deg);
    k_hist<<<(E + 255) / 256, 256, 0, stream>>>(ei, deg);
    k_scan_part<<<nb, 256, 0, stream>>>(deg, loc, partial);
    k_scan_tot<<<1, 512, 0, stream>>>(partial, nb);
    k_scan_add<<<nb, 256, 0, stream>>>(loc, partial, rowptr, cursor);
    k_scatter<<<(E + 255) / 256, 256, 0, stream>>>(ei, cursor, csr_src);

    k_node1<<<(N + 3) / 4, 256, 0, stream>>>(x, w1, as1, ad1, a1s, a1d);

    k_gat1<<<GAT1_BLOCKS, 256, 0, stream>>>(rowptr, deg, csr_src, x, w1, a1s, a1d,
                                            b1, w2, as2, ad2, h2, a2s, a2d);

    k_gat2<<<(N + 7) / 8, 256, 0, stream>>>(rowptr, deg, csr_src, h2, a2s, a2d, b2, hf);

    k_uv<<<1024, 256, 0, stream>>>(hf, mw1, u, v);

    k_mlp<<<(E + 7) / 8, 256, 0, stream>>>(ei, u, v, mb1, mw2, mb2, out);
}

// Round 5
// 588.205 us; speedup vs baseline: 1.2568x; 1.2568x over previous
//
#include <hip/hip_runtime.h>
#include <math.h>

#define N_NODES 100000
#define N_EDGES 1600000
#define NEG_SLOPE 0.2f
#define EPS 1e-16f

__device__ __forceinline__ float lrelu(float v) { return v > 0.f ? v : NEG_SLOPE * v; }

// ---------------------------------------------------------------- zero deg
__global__ void k_zero_deg(int* __restrict__ deg) {
    int i = blockIdx.x * blockDim.x + threadIdx.x;
    if (i < N_NODES) deg[i] = 0;
}

// ---------------------------------------------------------------- histogram of dst
__global__ void k_hist(const int* __restrict__ ei, int* __restrict__ deg) {
    int e = blockIdx.x * blockDim.x + threadIdx.x;
    if (e < N_EDGES) atomicAdd(&deg[ei[N_EDGES + e]], 1);
}

// ---------------------------------------------------------------- scan level 1
__global__ void k_scan_part(const int* __restrict__ deg, int* __restrict__ loc,
                            int* __restrict__ partial) {
    __shared__ int tmp[256];
    int i = blockIdx.x * 256 + threadIdx.x;
    int v = (i < N_NODES) ? deg[i] : 0;
    tmp[threadIdx.x] = v;
    __syncthreads();
    for (int off = 1; off < 256; off <<= 1) {
        int t = (threadIdx.x >= off) ? tmp[threadIdx.x - off] : 0;
        __syncthreads();
        tmp[threadIdx.x] += t;
        __syncthreads();
    }
    if (i < N_NODES) loc[i] = tmp[threadIdx.x] - v;   // exclusive
    if (threadIdx.x == 255) partial[blockIdx.x] = tmp[255];
}

// ---------------------------------------------------------------- scan level 2 (nb <= 512)
__global__ void k_scan_tot(int* __restrict__ partial, int nb) {
    __shared__ int tmp[512];
    int v = (threadIdx.x < nb) ? partial[threadIdx.x] : 0;
    tmp[threadIdx.x] = v;
    __syncthreads();
    for (int off = 1; off < 512; off <<= 1) {
        int t = (threadIdx.x >= off) ? tmp[threadIdx.x - off] : 0;
        __syncthreads();
        tmp[threadIdx.x] += t;
        __syncthreads();
    }
    if (threadIdx.x < nb) partial[threadIdx.x] = tmp[threadIdx.x] - v;  // exclusive
}

// ---------------------------------------------------------------- scan level 3 + cursor init
__global__ void k_scan_add(const int* __restrict__ loc, const int* __restrict__ partial,
                           int* __restrict__ rowptr, int* __restrict__ cursor) {
    int i = blockIdx.x * blockDim.x + threadIdx.x;
    if (i < N_NODES) {
        int r = loc[i] + partial[i >> 8];
        rowptr[i] = r;
        cursor[i] = r;
    }
}

// ---------------------------------------------------------------- scatter edges into CSR slots (by dst)
__global__ void k_scatter(const int* __restrict__ ei, int* __restrict__ cursor,
                          int* __restrict__ csr_src) {
    int e = blockIdx.x * blockDim.x + threadIdx.x;
    if (e < N_EDGES) {
        int dst = ei[N_EDGES + e];
        int pos = atomicAdd(&cursor[dst], 1);
        csr_src[pos] = ei[e];
    }
}

// ---------------------------------------------------------------- K-Q: qs[h] = W1_h^T a_src_h, qd[h] = W1_h^T a_dst_h  (24 floats)
__global__ void k_q(const float* __restrict__ w1, const float* __restrict__ as1,
                    const float* __restrict__ ad1, float* __restrict__ qv) {
    int t = threadIdx.x;
    if (t >= 24) return;
    int c = t % 3, h = (t / 3) % 4, side = t / 12;
    const float* att = side ? ad1 : as1;
    float acc = 0.f;
    for (int cc = 0; cc < 32; cc++)
        acc += att[h * 32 + cc] * w1[(h * 32 + cc) * 3 + c];
    qv[t] = acc;
}

// ---------------------------------------------------------------- K-NODE1: a1s/a1d = x . q   (1 thread/node)
__global__ void k_node1(const float* __restrict__ x, const float* __restrict__ qv,
                        float* __restrict__ a1s, float* __restrict__ a1d) {
    int n = blockIdx.x * blockDim.x + threadIdx.x;
    if (n >= N_NODES) return;
    float x0 = x[n * 3], x1 = x[n * 3 + 1], x2 = x[n * 3 + 2];
    float4 s, d;
    s.x = x0 * qv[0]  + x1 * qv[1]  + x2 * qv[2];
    s.y = x0 * qv[3]  + x1 * qv[4]  + x2 * qv[5];
    s.z = x0 * qv[6]  + x1 * qv[7]  + x2 * qv[8];
    s.w = x0 * qv[9]  + x1 * qv[10] + x2 * qv[11];
    d.x = x0 * qv[12] + x1 * qv[13] + x2 * qv[14];
    d.y = x0 * qv[15] + x1 * qv[16] + x2 * qv[17];
    d.z = x0 * qv[18] + x1 * qv[19] + x2 * qv[20];
    d.w = x0 * qv[21] + x1 * qv[22] + x2 * qv[23];
    ((float4*)a1s)[n] = s;
    ((float4*)a1d)[n] = d;
}

// ---------------------------------------------------------------- K-GAT1: linearity trick
// Phase A: 4 lanes/node (one per head) accumulate s3 = sum ex*x, den = sum ex.
// Phase B: per-wave per-node: f1 = ELU(W1.s3/den + b1), h2 = W2.f1, L2 logits.
#define G1_BLOCKS ((N_NODES + 63) / 64)
__global__ void k_gat1(const int* __restrict__ rowptr, const int* __restrict__ deg,
                       const int* __restrict__ csr_src,
                       const float* __restrict__ x, const float* __restrict__ w1,
                       const float* __restrict__ a1s, const float* __restrict__ a1d,
                       const float* __restrict__ b1, const float* __restrict__ w2,
                       const float* __restrict__ as2, const float* __restrict__ ad2,
                       float* __restrict__ h2, float* __restrict__ a2s, float* __restrict__ a2d) {
    __shared__ float w2t[128 * 33];   // [k][o], stride 33 -> conflict-free
    __shared__ float sm[64][16];      // per-node: 4 heads x {s0,s1,s2,den}
    __shared__ float f1s[4][128];
    int tid = threadIdx.x;
    for (int i = tid; i < 4096; i += 256) {
        int o = i >> 7, k = i & 127;
        w2t[k * 33 + o] = w2[i];
    }
    __syncthreads();
    int wave = tid >> 6, lane = tid & 63;

    // ---- phase A: node = block*64 + wave*16 + (lane>>2), head = lane&3
    int nl = wave * 16 + (lane >> 2);
    int h  = lane & 3;
    int n  = blockIdx.x * 64 + nl;
    if (n < N_NODES) {
        float adh = a1d[n * 4 + h];
        int beg = rowptr[n], cnt = deg[n];
        float s0 = 0.f, s1 = 0.f, s2 = 0.f, d = 0.f;
        for (int t = 0; t < cnt; t++) {
            int s = csr_src[beg + t];
            float ex = __expf(lrelu(a1s[s * 4 + h] + adh));
            s0 += ex * x[s * 3];
            s1 += ex * x[s * 3 + 1];
            s2 += ex * x[s * 3 + 2];
            d  += ex;
        }
        float4 r; r.x = s0; r.y = s1; r.z = s2; r.w = d;
        *(float4*)&sm[nl][h * 4] = r;
    }
    // same-wave LDS write->read below: no barrier needed

    // ---- phase B: wave processes its own 16 nodes
    int j = lane, j2 = lane + 64;
    int h0 = j >> 5;
    float wa0 = w1[j * 3], wa1 = w1[j * 3 + 1], wa2 = w1[j * 3 + 2];
    float wb0 = w1[j2 * 3], wb1 = w1[j2 * 3 + 1], wb2 = w1[j2 * 3 + 2];
    float b1j = b1[j], b1j2 = b1[j2];
    int o = lane & 31, half = lane >> 5;
    float as2o = as2[o], ad2o = ad2[o];
    int k0 = half * 64;
    const float* f = f1s[wave];

    #pragma unroll 1
    for (int i = 0; i < 16; i++) {
        int n2 = blockIdx.x * 64 + wave * 16 + i;
        if (n2 >= N_NODES) break;
        const float* S = sm[wave * 16 + i];
        float v0 = (wa0 * S[h0 * 4] + wa1 * S[h0 * 4 + 1] + wa2 * S[h0 * 4 + 2])
                   / (S[h0 * 4 + 3] + EPS) + b1j;
        float v1 = (wb0 * S[(2 + h0) * 4] + wb1 * S[(2 + h0) * 4 + 1] + wb2 * S[(2 + h0) * 4 + 2])
                   / (S[(2 + h0) * 4 + 3] + EPS) + b1j2;
        f1s[wave][j]  = v0 > 0.f ? v0 : expm1f(v0);
        f1s[wave][j2] = v1 > 0.f ? v1 : expm1f(v1);
        float acc = 0.f;
        #pragma unroll 8
        for (int t = 0; t < 64; t++)
            acc += f[k0 + t] * w2t[(k0 + t) * 33 + o];
        acc += __shfl_down(acc, 32);
        if (half == 0) {
            h2[n2 * 32 + o] = acc;
            float ps = acc * as2o, pd = acc * ad2o;
            #pragma unroll
            for (int off = 16; off; off >>= 1) {
                ps += __shfl_xor(ps, off);
                pd += __shfl_xor(pd, off);
            }
            if (o == 0) { a2s[n2] = ps; a2d[n2] = pd; }
        }
    }
}

// ---------------------------------------------------------------- K-GAT2: layer-2 gather + finalize + fused u/v matvecs
// 32 lanes per node; mw1 rows in registers; u gets mb1 folded in
#define G2_BLOCKS 4096
__global__ void k_gat2(const int* __restrict__ rowptr, const int* __restrict__ deg,
                       const int* __restrict__ csr_src,
                       const float* __restrict__ h2, const float* __restrict__ a2s,
                       const float* __restrict__ a2d, const float* __restrict__ b2,
                       const float* __restrict__ mw1, const float* __restrict__ mb1,
                       float* __restrict__ u, float* __restrict__ v) {
    int tid = threadIdx.x;
    int lane = tid & 63;
    int c = lane & 31, seg = lane >> 5;
    float A[32], B[32];
    const float4* ap = (const float4*)(mw1 + c * 64);
    #pragma unroll
    for (int q = 0; q < 8; q++) {
        float4 t = ap[q];
        A[q * 4 + 0] = t.x; A[q * 4 + 1] = t.y; A[q * 4 + 2] = t.z; A[q * 4 + 3] = t.w;
    }
    #pragma unroll
    for (int q = 0; q < 8; q++) {
        float4 t = ap[8 + q];
        B[q * 4 + 0] = t.x; B[q * 4 + 1] = t.y; B[q * 4 + 2] = t.z; B[q * 4 + 3] = t.w;
    }
    float mb1c = mb1[c], b2c = b2[c];
    int base = (blockIdx.x * 4 + (tid >> 6)) * 2 + seg;
    const int stride = G2_BLOCKS * 8;
    for (int n = base; n < N_NODES; n += stride) {
        float ad = a2d[n];
        int beg = rowptr[n], cnt = deg[n];
        float acc = 0.f, den = 0.f;
        for (int t = 0; t < cnt; t++) {
            int s = csr_src[beg + t];
            float ex = __expf(lrelu(a2s[s] + ad));
            acc += ex * h2[s * 32 + c];
            den += ex;
        }
        float hfc = acc / (den + EPS) + b2c;
        float uu = mb1c, vv = 0.f;
        #pragma unroll
        for (int k = 0; k < 32; k++) {
            float hk = __shfl(hfc, k, 32);
            uu += A[k] * hk;
            vv += B[k] * hk;
        }
        u[n * 32 + c] = uu;
        v[n * 32 + c] = vv;
    }
}

// ---------------------------------------------------------------- K-MLP: 8 lanes/edge, grid-stride
#define MLP_BLOCKS 4096
__global__ void k_mlp(const int* __restrict__ ei, const float* __restrict__ u,
                      const float* __restrict__ v, const float* __restrict__ mw2,
                      const float* __restrict__ mb2, float* __restrict__ out) {
    int tid = threadIdx.x;
    int q = tid & 7;
    float4 w2q = ((const float4*)mw2)[q];
    float mb20 = mb2[0];
    int g = blockIdx.x * 32 + (tid >> 3);
    const int stride = MLP_BLOCKS * 32;
    for (int e = g; e < N_EDGES; e += stride) {
        int src = ei[e], dst = ei[N_EDGES + e];
        float4 ua = *(const float4*)(u + src * 32 + q * 4);
        float4 va = *(const float4*)(v + dst * 32 + q * 4);
        float s = fmaxf(ua.x + va.x, 0.f) * w2q.x
                + fmaxf(ua.y + va.y, 0.f) * w2q.y
                + fmaxf(ua.z + va.z, 0.f) * w2q.z
                + fmaxf(ua.w + va.w, 0.f) * w2q.w;
        s += __shfl_xor(s, 1, 8);
        s += __shfl_xor(s, 2, 8);
        s += __shfl_xor(s, 4, 8);
        if (q == 0) out[e] = fmaxf(s + mb20, 0.f);
    }
}

// ---------------------------------------------------------------- launch
extern "C" void kernel_launch(void* const* d_in, const int* in_sizes, int n_in,
                              void* d_out, int out_size, void* d_ws, size_t ws_size,
                              hipStream_t stream) {
    const float* x    = (const float*)d_in[0];
    const int*   ei   = (const int*)d_in[1];
    const float* w1   = (const float*)d_in[2];
    const float* as1  = (const float*)d_in[3];
    const float* ad1  = (const float*)d_in[4];
    const float* b1   = (const float*)d_in[5];
    const float* w2   = (const float*)d_in[6];
    const float* as2  = (const float*)d_in[7];
    const float* ad2  = (const float*)d_in[8];
    const float* b2   = (const float*)d_in[9];
    const float* mw1  = (const float*)d_in[10];
    const float* mb1  = (const float*)d_in[11];
    const float* mw2  = (const float*)d_in[12];
    const float* mb2  = (const float*)d_in[13];
    float* out = (float*)d_out;

    const int N = N_NODES, E = N_EDGES;
    int* deg     = (int*)d_ws;           // N
    int* rowptr  = deg + N;              // N
    int* cursor  = rowptr + N;           // N
    int* loc     = cursor + N;           // N
    int* partial = loc + N;              // 512
    int* csr_src = partial + 512;        // E
    float* a1s   = (float*)(csr_src + E);// 4N
    float* a1d   = a1s + 4 * N;          // 4N
    float* h2    = a1d + 4 * N;          // 32N
    float* a2s   = h2 + 32 * N;          // N
    float* a2d   = a2s + N;              // N
    float* u     = a2d + N;              // 32N
    float* v     = u + 32 * N;           // 32N
    float* qv    = v + 32 * N;           // 24

    const int nb = (N + 255) / 256;

    k_zero_deg<<<nb, 256, 0, stream>>>(deg);
    k_hist<<<(E + 255) / 256, 256, 0, stream>>>(ei, deg);
    k_scan_part<<<nb, 256, 0, stream>>>(deg, loc, partial);
    k_scan_tot<<<1, 512, 0, stream>>>(partial, nb);
    k_scan_add<<<nb, 256, 0, stream>>>(loc, partial, rowptr, cursor);
    k_scatter<<<(E + 255) / 256, 256, 0, stream>>>(ei, cursor, csr_src);

    k_q<<<1, 32, 0, stream>>>(w1, as1, ad1, qv);
    k_node1<<<nb, 256, 0, stream>>>(x, qv, a1s, a1d);

    k_gat1<<<G1_BLOCKS, 256, 0, stream>>>(rowptr, deg, csr_src, x, w1, a1s, a1d,
                                          b1, w2, as2, ad2, h2, a2s, a2d);

    k_gat2<<<G2_BLOCKS, 256, 0, stream>>>(rowptr, deg, csr_src, h2, a2s, a2d, b2,
                                          mw1, mb1, u, v);

    k_mlp<<<MLP_BLOCKS, 256, 0, stream>>>(ei, u, v, mw2, mb2, out);
}

// Round 6
// 490.931 us; speedup vs baseline: 1.5059x; 1.1981x over previous
//
#include <hip/hip_runtime.h>
#include <math.h>

#define N_NODES 100000
#define N_EDGES 1600000
#define NEG_SLOPE 0.2f
#define EPS 1e-16f

__device__ __forceinline__ float lrelu(float v) { return v > 0.f ? v : NEG_SLOPE * v; }

// ---------------------------------------------------------------- zero deg
__global__ void k_zero_deg(int* __restrict__ deg) {
    int i = blockIdx.x * blockDim.x + threadIdx.x;
    if (i < N_NODES) deg[i] = 0;
}

// ---------------------------------------------------------------- histogram of dst
__global__ void k_hist(const int* __restrict__ ei, int* __restrict__ deg) {
    int e = blockIdx.x * blockDim.x + threadIdx.x;
    if (e < N_EDGES) atomicAdd(&deg[ei[N_EDGES + e]], 1);
}

// ---------------------------------------------------------------- scan level 1
__global__ void k_scan_part(const int* __restrict__ deg, int* __restrict__ loc,
                            int* __restrict__ partial) {
    __shared__ int tmp[256];
    int i = blockIdx.x * 256 + threadIdx.x;
    int v = (i < N_NODES) ? deg[i] : 0;
    tmp[threadIdx.x] = v;
    __syncthreads();
    for (int off = 1; off < 256; off <<= 1) {
        int t = (threadIdx.x >= off) ? tmp[threadIdx.x - off] : 0;
        __syncthreads();
        tmp[threadIdx.x] += t;
        __syncthreads();
    }
    if (i < N_NODES) loc[i] = tmp[threadIdx.x] - v;   // exclusive
    if (threadIdx.x == 255) partial[blockIdx.x] = tmp[255];
}

// ---------------------------------------------------------------- scan level 2 (nb <= 512)
__global__ void k_scan_tot(int* __restrict__ partial, int nb) {
    __shared__ int tmp[512];
    int v = (threadIdx.x < nb) ? partial[threadIdx.x] : 0;
    tmp[threadIdx.x] = v;
    __syncthreads();
    for (int off = 1; off < 512; off <<= 1) {
        int t = (threadIdx.x >= off) ? tmp[threadIdx.x - off] : 0;
        __syncthreads();
        tmp[threadIdx.x] += t;
        __syncthreads();
    }
    if (threadIdx.x < nb) partial[threadIdx.x] = tmp[threadIdx.x] - v;  // exclusive
}

// ---------------------------------------------------------------- scan level 3 + cursor init
__global__ void k_scan_add(const int* __restrict__ loc, const int* __restrict__ partial,
                           int* __restrict__ rowptr, int* __restrict__ cursor) {
    int i = blockIdx.x * blockDim.x + threadIdx.x;
    if (i < N_NODES) {
        int r = loc[i] + partial[i >> 8];
        rowptr[i] = r;
        cursor[i] = r;
    }
}

// ---------------------------------------------------------------- scatter edges into CSR slots (by dst)
__global__ void k_scatter(const int* __restrict__ ei, int* __restrict__ cursor,
                          int* __restrict__ csr_src) {
    int e = blockIdx.x * blockDim.x + threadIdx.x;
    if (e < N_EDGES) {
        int dst = ei[N_EDGES + e];
        int pos = atomicAdd(&cursor[dst], 1);
        csr_src[pos] = ei[e];
    }
}

// ---------------------------------------------------------------- K-Q: qs[h] = W1_h^T a_src_h, qd[h] = W1_h^T a_dst_h  (24 floats)
__global__ void k_q(const float* __restrict__ w1, const float* __restrict__ as1,
                    const float* __restrict__ ad1, float* __restrict__ qv) {
    int t = threadIdx.x;
    if (t >= 24) return;
    int c = t % 3, h = (t / 3) % 4, side = t / 12;
    const float* att = side ? ad1 : as1;
    float acc = 0.f;
    for (int cc = 0; cc < 32; cc++)
        acc += att[h * 32 + cc] * w1[(h * 32 + cc) * 3 + c];
    qv[t] = acc;
}

// ---------------------------------------------------------------- K-NODE1: a1s/a1d = x . q   (1 thread/node)
__global__ void k_node1(const float* __restrict__ x, const float* __restrict__ qv,
                        float* __restrict__ a1s, float* __restrict__ a1d) {
    int n = blockIdx.x * blockDim.x + threadIdx.x;
    if (n >= N_NODES) return;
    float x0 = x[n * 3], x1 = x[n * 3 + 1], x2 = x[n * 3 + 2];
    float4 s, d;
    s.x = x0 * qv[0]  + x1 * qv[1]  + x2 * qv[2];
    s.y = x0 * qv[3]  + x1 * qv[4]  + x2 * qv[5];
    s.z = x0 * qv[6]  + x1 * qv[7]  + x2 * qv[8];
    s.w = x0 * qv[9]  + x1 * qv[10] + x2 * qv[11];
    d.x = x0 * qv[12] + x1 * qv[13] + x2 * qv[14];
    d.y = x0 * qv[15] + x1 * qv[16] + x2 * qv[17];
    d.z = x0 * qv[18] + x1 * qv[19] + x2 * qv[20];
    d.w = x0 * qv[21] + x1 * qv[22] + x2 * qv[23];
    ((float4*)a1s)[n] = s;
    ((float4*)a1d)[n] = d;
}

// ---------------------------------------------------------------- K-GAT1: linearity trick, w2 in registers
// Phase A: 4 lanes/node (one per head) accumulate s3 = sum ex*x, den = sum ex (unroll 4).
// Phase B: f1 = ELU(W1.s3/den + b1) -> LDS; h2 = W2.f1 with per-lane w2 register column.
#define G1_BLOCKS ((N_NODES + 63) / 64)
__global__ void k_gat1(const int* __restrict__ rowptr, const int* __restrict__ deg,
                       const int* __restrict__ csr_src,
                       const float* __restrict__ x, const float* __restrict__ w1,
                       const float* __restrict__ a1s, const float* __restrict__ a1d,
                       const float* __restrict__ b1, const float* __restrict__ w2,
                       const float* __restrict__ as2, const float* __restrict__ ad2,
                       float* __restrict__ h2, float* __restrict__ a2s, float* __restrict__ a2d) {
    __shared__ float sm[64][16];      // per-node: 4 heads x {s0,s1,s2,den}
    __shared__ float f1s[4][128];
    int tid = threadIdx.x;
    int wave = tid >> 6, lane = tid & 63;
    int o = lane & 31, half = lane >> 5;
    int k0 = half * 64;

    // per-lane w2 column: w2[o][k0..k0+63] in 64 VGPRs (16 x dwordx4)
    float w2r[64];
    {
        const float4* wp = (const float4*)(w2 + o * 128 + k0);
        #pragma unroll
        for (int q = 0; q < 16; q++) {
            float4 t = wp[q];
            w2r[q * 4 + 0] = t.x; w2r[q * 4 + 1] = t.y;
            w2r[q * 4 + 2] = t.z; w2r[q * 4 + 3] = t.w;
        }
    }

    // ---- phase A: node = block*64 + wave*16 + (lane>>2), head = lane&3
    int nl = wave * 16 + (lane >> 2);
    int h  = lane & 3;
    int n  = blockIdx.x * 64 + nl;
    if (n < N_NODES) {
        float adh = a1d[n * 4 + h];
        int beg = rowptr[n], cnt = deg[n];
        float s0a = 0.f, s1a = 0.f, s2a = 0.f, da = 0.f;
        int t = 0;
        for (; t + 4 <= cnt; t += 4) {
            int s0 = csr_src[beg + t + 0], s1 = csr_src[beg + t + 1];
            int s2 = csr_src[beg + t + 2], s3 = csr_src[beg + t + 3];
            float l0 = a1s[s0 * 4 + h], l1 = a1s[s1 * 4 + h];
            float l2 = a1s[s2 * 4 + h], l3 = a1s[s3 * 4 + h];
            float x00 = x[s0 * 3], x01 = x[s0 * 3 + 1], x02 = x[s0 * 3 + 2];
            float x10 = x[s1 * 3], x11 = x[s1 * 3 + 1], x12 = x[s1 * 3 + 2];
            float x20 = x[s2 * 3], x21 = x[s2 * 3 + 1], x22 = x[s2 * 3 + 2];
            float x30 = x[s3 * 3], x31 = x[s3 * 3 + 1], x32 = x[s3 * 3 + 2];
            float e0 = __expf(lrelu(l0 + adh));
            float e1 = __expf(lrelu(l1 + adh));
            float e2 = __expf(lrelu(l2 + adh));
            float e3 = __expf(lrelu(l3 + adh));
            s0a += e0 * x00 + e1 * x10 + e2 * x20 + e3 * x30;
            s1a += e0 * x01 + e1 * x11 + e2 * x21 + e3 * x31;
            s2a += e0 * x02 + e1 * x12 + e2 * x22 + e3 * x32;
            da  += e0 + e1 + e2 + e3;
        }
        for (; t < cnt; t++) {
            int s = csr_src[beg + t];
            float ex = __expf(lrelu(a1s[s * 4 + h] + adh));
            s0a += ex * x[s * 3];
            s1a += ex * x[s * 3 + 1];
            s2a += ex * x[s * 3 + 2];
            da  += ex;
        }
        float4 r; r.x = s0a; r.y = s1a; r.z = s2a; r.w = da;
        *(float4*)&sm[nl][h * 4] = r;
    }
    // same-wave LDS write->read below: no barrier needed

    // ---- phase B: wave processes its own 16 nodes
    int j = lane, j2 = lane + 64;
    int h0 = j >> 5;
    float wa0 = w1[j * 3], wa1 = w1[j * 3 + 1], wa2 = w1[j * 3 + 2];
    float wb0 = w1[j2 * 3], wb1 = w1[j2 * 3 + 1], wb2 = w1[j2 * 3 + 2];
    float b1j = b1[j], b1j2 = b1[j2];
    float as2o = as2[o], ad2o = ad2[o];
    const float* f = f1s[wave];

    #pragma unroll 1
    for (int i = 0; i < 16; i++) {
        int n2 = blockIdx.x * 64 + wave * 16 + i;
        if (n2 >= N_NODES) break;
        const float* S = sm[wave * 16 + i];
        float v0 = (wa0 * S[h0 * 4] + wa1 * S[h0 * 4 + 1] + wa2 * S[h0 * 4 + 2])
                   / (S[h0 * 4 + 3] + EPS) + b1j;
        float v1 = (wb0 * S[(2 + h0) * 4] + wb1 * S[(2 + h0) * 4 + 1] + wb2 * S[(2 + h0) * 4 + 2])
                   / (S[(2 + h0) * 4 + 3] + EPS) + b1j2;
        f1s[wave][j]  = v0 > 0.f ? v0 : expm1f(v0);
        f1s[wave][j2] = v1 > 0.f ? v1 : expm1f(v1);
        float acc = 0.f;
        #pragma unroll
        for (int t = 0; t < 64; t++)
            acc += f[k0 + t] * w2r[t];      // f: 2-addr broadcast ds_read (free); w2r: VGPR
        acc += __shfl_down(acc, 32);
        if (half == 0) {
            h2[n2 * 32 + o] = acc;
            float ps = acc * as2o, pd = acc * ad2o;
            #pragma unroll
            for (int off = 16; off; off >>= 1) {
                ps += __shfl_xor(ps, off);
                pd += __shfl_xor(pd, off);
            }
            if (o == 0) { a2s[n2] = ps; a2d[n2] = pd; }
        }
    }
}

// ---------------------------------------------------------------- K-GAT2: layer-2 gather + finalize + fused u/v matvecs
// 32 lanes per node; edge loop unrolled x4 (batched loads); mw1 rows in registers
#define G2_BLOCKS 4096
__global__ void k_gat2(const int* __restrict__ rowptr, const int* __restrict__ deg,
                       const int* __restrict__ csr_src,
                       const float* __restrict__ h2, const float* __restrict__ a2s,
                       const float* __restrict__ a2d, const float* __restrict__ b2,
                       const float* __restrict__ mw1, const float* __restrict__ mb1,
                       float* __restrict__ u, float* __restrict__ v) {
    int tid = threadIdx.x;
    int lane = tid & 63;
    int c = lane & 31, seg = lane >> 5;
    float A[32], B[32];
    const float4* ap = (const float4*)(mw1 + c * 64);
    #pragma unroll
    for (int q = 0; q < 8; q++) {
        float4 t = ap[q];
        A[q * 4 + 0] = t.x; A[q * 4 + 1] = t.y; A[q * 4 + 2] = t.z; A[q * 4 + 3] = t.w;
    }
    #pragma unroll
    for (int q = 0; q < 8; q++) {
        float4 t = ap[8 + q];
        B[q * 4 + 0] = t.x; B[q * 4 + 1] = t.y; B[q * 4 + 2] = t.z; B[q * 4 + 3] = t.w;
    }
    float mb1c = mb1[c], b2c = b2[c];
    int base = (blockIdx.x * 4 + (tid >> 6)) * 2 + seg;
    const int stride = G2_BLOCKS * 8;
    for (int n = base; n < N_NODES; n += stride) {
        float ad = a2d[n];
        int beg = rowptr[n], cnt = deg[n];
        float acc = 0.f, den = 0.f;
        int t = 0;
        for (; t + 4 <= cnt; t += 4) {
            int s0 = csr_src[beg + t + 0], s1 = csr_src[beg + t + 1];
            int s2 = csr_src[beg + t + 2], s3 = csr_src[beg + t + 3];
            float l0 = a2s[s0], l1 = a2s[s1], l2 = a2s[s2], l3 = a2s[s3];
            float g0 = h2[s0 * 32 + c], g1 = h2[s1 * 32 + c];
            float g2 = h2[s2 * 32 + c], g3 = h2[s3 * 32 + c];
            float e0 = __expf(lrelu(l0 + ad));
            float e1 = __expf(lrelu(l1 + ad));
            float e2 = __expf(lrelu(l2 + ad));
            float e3 = __expf(lrelu(l3 + ad));
            acc += e0 * g0 + e1 * g1 + e2 * g2 + e3 * g3;
            den += e0 + e1 + e2 + e3;
        }
        for (; t < cnt; t++) {
            int s = csr_src[beg + t];
            float ex = __expf(lrelu(a2s[s] + ad));
            acc += ex * h2[s * 32 + c];
            den += ex;
        }
        float hfc = acc / (den + EPS) + b2c;
        float uu = mb1c, vv = 0.f;
        #pragma unroll
        for (int k = 0; k < 32; k++) {
            float hk = __shfl(hfc, k, 32);
            uu += A[k] * hk;
            vv += B[k] * hk;
        }
        u[n * 32 + c] = uu;
        v[n * 32 + c] = vv;
    }
}

// ---------------------------------------------------------------- K-MLP: 8 lanes/edge, 2 edges per group per iter
#define MLP_BLOCKS 4096
__global__ void k_mlp(const int* __restrict__ ei, const float* __restrict__ u,
                      const float* __restrict__ v, const float* __restrict__ mw2,
                      const float* __restrict__ mb2, float* __restrict__ out) {
    int tid = threadIdx.x;
    int q = tid & 7;
    float4 w2q = ((const float4*)mw2)[q];
    float mb20 = mb2[0];
    int g = blockIdx.x * 32 + (tid >> 3);
    const int stride = MLP_BLOCKS * 64;
    for (int e = g * 2; e < N_EDGES; e += stride) {
        int e1ok = (e + 1 < N_EDGES);
        int src0 = ei[e], dst0 = ei[N_EDGES + e];
        int src1 = ei[e + e1ok], dst1 = ei[N_EDGES + e + e1ok];
        float4 ua0 = *(const float4*)(u + src0 * 32 + q * 4);
        float4 va0 = *(const float4*)(v + dst0 * 32 + q * 4);
        float4 ua1 = *(const float4*)(u + src1 * 32 + q * 4);
        float4 va1 = *(const float4*)(v + dst1 * 32 + q * 4);
        float s0 = fmaxf(ua0.x + va0.x, 0.f) * w2q.x
                 + fmaxf(ua0.y + va0.y, 0.f) * w2q.y
                 + fmaxf(ua0.z + va0.z, 0.f) * w2q.z
                 + fmaxf(ua0.w + va0.w, 0.f) * w2q.w;
        float s1 = fmaxf(ua1.x + va1.x, 0.f) * w2q.x
                 + fmaxf(ua1.y + va1.y, 0.f) * w2q.y
                 + fmaxf(ua1.z + va1.z, 0.f) * w2q.z
                 + fmaxf(ua1.w + va1.w, 0.f) * w2q.w;
        s0 += __shfl_xor(s0, 1, 8); s0 += __shfl_xor(s0, 2, 8); s0 += __shfl_xor(s0, 4, 8);
        s1 += __shfl_xor(s1, 1, 8); s1 += __shfl_xor(s1, 2, 8); s1 += __shfl_xor(s1, 4, 8);
        if (q == 0) {
            out[e] = fmaxf(s0 + mb20, 0.f);
            if (e1ok) out[e + 1] = fmaxf(s1 + mb20, 0.f);
        }
    }
}

// ---------------------------------------------------------------- launch
extern "C" void kernel_launch(void* const* d_in, const int* in_sizes, int n_in,
                              void* d_out, int out_size, void* d_ws, size_t ws_size,
                              hipStream_t stream) {
    const float* x    = (const float*)d_in[0];
    const int*   ei   = (const int*)d_in[1];
    const float* w1   = (const float*)d_in[2];
    const float* as1  = (const float*)d_in[3];
    const float* ad1  = (const float*)d_in[4];
    const float* b1   = (const float*)d_in[5];
    const float* w2   = (const float*)d_in[6];
    const float* as2  = (const float*)d_in[7];
    const float* ad2  = (const float*)d_in[8];
    const float* b2   = (const float*)d_in[9];
    const float* mw1  = (const float*)d_in[10];
    const float* mb1  = (const float*)d_in[11];
    const float* mw2  = (const float*)d_in[12];
    const float* mb2  = (const float*)d_in[13];
    float* out = (float*)d_out;

    const int N = N_NODES, E = N_EDGES;
    int* deg     = (int*)d_ws;           // N
    int* rowptr  = deg + N;              // N
    int* cursor  = rowptr + N;           // N
    int* loc     = cursor + N;           // N
    int* partial = loc + N;              // 512
    int* csr_src = partial + 512;        // E
    float* a1s   = (float*)(csr_src + E);// 4N
    float* a1d   = a1s + 4 * N;          // 4N
    float* h2    = a1d + 4 * N;          // 32N
    float* a2s   = h2 + 32 * N;          // N
    float* a2d   = a2s + N;              // N
    float* u     = a2d + N;              // 32N
    float* v     = u + 32 * N;           // 32N
    float* qv    = v + 32 * N;           // 24

    const int nb = (N + 255) / 256;

    k_zero_deg<<<nb, 256, 0, stream>>>(deg);
    k_hist<<<(E + 255) / 256, 256, 0, stream>>>(ei, deg);
    k_scan_part<<<nb, 256, 0, stream>>>(deg, loc, partial);
    k_scan_tot<<<1, 512, 0, stream>>>(partial, nb);
    k_scan_add<<<nb, 256, 0, stream>>>(loc, partial, rowptr, cursor);
    k_scatter<<<(E + 255) / 256, 256, 0, stream>>>(ei, cursor, csr_src);

    k_q<<<1, 32, 0, stream>>>(w1, as1, ad1, qv);
    k_node1<<<nb, 256, 0, stream>>>(x, qv, a1s, a1d);

    k_gat1<<<G1_BLOCKS, 256, 0, stream>>>(rowptr, deg, csr_src, x, w1, a1s, a1d,
                                          b1, w2, as2, ad2, h2, a2s, a2d);

    k_gat2<<<G2_BLOCKS, 256, 0, stream>>>(rowptr, deg, csr_src, h2, a2s, a2d, b2,
                                          mw1, mb1, u, v);

    k_mlp<<<MLP_BLOCKS, 256, 0, stream>>>(ei, u, v, mw2, mb2, out);
}

// Round 7
// 490.788 us; speedup vs baseline: 1.5063x; 1.0003x over previous
//
#include <hip/hip_runtime.h>
#include <math.h>

#define N_NODES 100000
#define N_EDGES 1600000
#define NEG_SLOPE 0.2f
#define EPS 1e-16f
#define SCAT_PASSES 8

__device__ __forceinline__ float lrelu(float v) { return v > 0.f ? v : NEG_SLOPE * v; }

// ---------------------------------------------------------------- zero deg
__global__ void k_zero_deg(int* __restrict__ deg) {
    int i = blockIdx.x * blockDim.x + threadIdx.x;
    if (i < N_NODES) deg[i] = 0;
}

// ---------------------------------------------------------------- histogram of dst
__global__ void k_hist(const int* __restrict__ ei, int* __restrict__ deg) {
    int e = blockIdx.x * blockDim.x + threadIdx.x;
    if (e < N_EDGES) atomicAdd(&deg[ei[N_EDGES + e]], 1);
}

// ---------------------------------------------------------------- scan level 1
__global__ void k_scan_part(const int* __restrict__ deg, int* __restrict__ loc,
                            int* __restrict__ partial) {
    __shared__ int tmp[256];
    int i = blockIdx.x * 256 + threadIdx.x;
    int v = (i < N_NODES) ? deg[i] : 0;
    tmp[threadIdx.x] = v;
    __syncthreads();
    for (int off = 1; off < 256; off <<= 1) {
        int t = (threadIdx.x >= off) ? tmp[threadIdx.x - off] : 0;
        __syncthreads();
        tmp[threadIdx.x] += t;
        __syncthreads();
    }
    if (i < N_NODES) loc[i] = tmp[threadIdx.x] - v;   // exclusive
    if (threadIdx.x == 255) partial[blockIdx.x] = tmp[255];
}

// ---------------------------------------------------------------- scan level 2 (nb <= 512)
__global__ void k_scan_tot(int* __restrict__ partial, int nb) {
    __shared__ int tmp[512];
    int v = (threadIdx.x < nb) ? partial[threadIdx.x] : 0;
    tmp[threadIdx.x] = v;
    __syncthreads();
    for (int off = 1; off < 512; off <<= 1) {
        int t = (threadIdx.x >= off) ? tmp[threadIdx.x - off] : 0;
        __syncthreads();
        tmp[threadIdx.x] += t;
        __syncthreads();
    }
    if (threadIdx.x < nb) partial[threadIdx.x] = tmp[threadIdx.x] - v;  // exclusive
}

// ---------------------------------------------------------------- scan level 3 + cursor init
__global__ void k_scan_add(const int* __restrict__ loc, const int* __restrict__ partial,
                           int* __restrict__ rowptr, int* __restrict__ cursor) {
    int i = blockIdx.x * blockDim.x + threadIdx.x;
    if (i < N_NODES) {
        int r = loc[i] + partial[i >> 8];
        rowptr[i] = r;
        cursor[i] = r;
    }
}

// ---------------------------------------------------------------- range-restricted scatter: only dst in [lo,hi)
// keeps writes concentrated in a ~800KB csr region -> lines stay hot in L2
__global__ void k_scatter(const int* __restrict__ ei, int* __restrict__ cursor,
                          int* __restrict__ csr_src, int lo, int hi) {
    int e = blockIdx.x * blockDim.x + threadIdx.x;
    if (e < N_EDGES) {
        int dst = ei[N_EDGES + e];
        if (dst >= lo && dst < hi) {
            int pos = atomicAdd(&cursor[dst], 1);
            csr_src[pos] = ei[e];
        }
    }
}

// ---------------------------------------------------------------- K-Q: qs[h] = W1_h^T a_src_h, qd[h] = W1_h^T a_dst_h  (24 floats)
__global__ void k_q(const float* __restrict__ w1, const float* __restrict__ as1,
                    const float* __restrict__ ad1, float* __restrict__ qv) {
    int t = threadIdx.x;
    if (t >= 24) return;
    int c = t % 3, h = (t / 3) % 4, side = t / 12;
    const float* att = side ? ad1 : as1;
    float acc = 0.f;
    for (int cc = 0; cc < 32; cc++)
        acc += att[h * 32 + cc] * w1[(h * 32 + cc) * 3 + c];
    qv[t] = acc;
}

// ---------------------------------------------------------------- K-NODE1: a1s/a1d = x . q   (1 thread/node)
__global__ void k_node1(const float* __restrict__ x, const float* __restrict__ qv,
                        float* __restrict__ a1s, float* __restrict__ a1d) {
    int n = blockIdx.x * blockDim.x + threadIdx.x;
    if (n >= N_NODES) return;
    float x0 = x[n * 3], x1 = x[n * 3 + 1], x2 = x[n * 3 + 2];
    float4 s, d;
    s.x = x0 * qv[0]  + x1 * qv[1]  + x2 * qv[2];
    s.y = x0 * qv[3]  + x1 * qv[4]  + x2 * qv[5];
    s.z = x0 * qv[6]  + x1 * qv[7]  + x2 * qv[8];
    s.w = x0 * qv[9]  + x1 * qv[10] + x2 * qv[11];
    d.x = x0 * qv[12] + x1 * qv[13] + x2 * qv[14];
    d.y = x0 * qv[15] + x1 * qv[16] + x2 * qv[17];
    d.z = x0 * qv[18] + x1 * qv[19] + x2 * qv[20];
    d.w = x0 * qv[21] + x1 * qv[22] + x2 * qv[23];
    ((float4*)a1s)[n] = s;
    ((float4*)a1d)[n] = d;
}

// ---------------------------------------------------------------- K-GAT1: linearity trick, w2 in registers
#define G1_BLOCKS ((N_NODES + 63) / 64)
__global__ void k_gat1(const int* __restrict__ rowptr, const int* __restrict__ deg,
                       const int* __restrict__ csr_src,
                       const float* __restrict__ x, const float* __restrict__ w1,
                       const float* __restrict__ a1s, const float* __restrict__ a1d,
                       const float* __restrict__ b1, const float* __restrict__ w2,
                       const float* __restrict__ as2, const float* __restrict__ ad2,
                       float* __restrict__ h2, float* __restrict__ a2s, float* __restrict__ a2d) {
    __shared__ float sm[64][16];      // per-node: 4 heads x {s0,s1,s2,den}
    __shared__ float f1s[4][128];
    int tid = threadIdx.x;
    int wave = tid >> 6, lane = tid & 63;
    int o = lane & 31, half = lane >> 5;
    int k0 = half * 64;

    // per-lane w2 column: w2[o][k0..k0+63] in 64 VGPRs
    float w2r[64];
    {
        const float4* wp = (const float4*)(w2 + o * 128 + k0);
        #pragma unroll
        for (int q = 0; q < 16; q++) {
            float4 t = wp[q];
            w2r[q * 4 + 0] = t.x; w2r[q * 4 + 1] = t.y;
            w2r[q * 4 + 2] = t.z; w2r[q * 4 + 3] = t.w;
        }
    }

    // ---- phase A: node = block*64 + wave*16 + (lane>>2), head = lane&3
    int nl = wave * 16 + (lane >> 2);
    int h  = lane & 3;
    int n  = blockIdx.x * 64 + nl;
    if (n < N_NODES) {
        float adh = a1d[n * 4 + h];
        int beg = rowptr[n], cnt = deg[n];
        float s0a = 0.f, s1a = 0.f, s2a = 0.f, da = 0.f;
        int t = 0;
        for (; t + 4 <= cnt; t += 4) {
            int s0 = csr_src[beg + t + 0], s1 = csr_src[beg + t + 1];
            int s2 = csr_src[beg + t + 2], s3 = csr_src[beg + t + 3];
            float l0 = a1s[s0 * 4 + h], l1 = a1s[s1 * 4 + h];
            float l2 = a1s[s2 * 4 + h], l3 = a1s[s3 * 4 + h];
            float x00 = x[s0 * 3], x01 = x[s0 * 3 + 1], x02 = x[s0 * 3 + 2];
            float x10 = x[s1 * 3], x11 = x[s1 * 3 + 1], x12 = x[s1 * 3 + 2];
            float x20 = x[s2 * 3], x21 = x[s2 * 3 + 1], x22 = x[s2 * 3 + 2];
            float x30 = x[s3 * 3], x31 = x[s3 * 3 + 1], x32 = x[s3 * 3 + 2];
            float e0 = __expf(lrelu(l0 + adh));
            float e1 = __expf(lrelu(l1 + adh));
            float e2 = __expf(lrelu(l2 + adh));
            float e3 = __expf(lrelu(l3 + adh));
            s0a += e0 * x00 + e1 * x10 + e2 * x20 + e3 * x30;
            s1a += e0 * x01 + e1 * x11 + e2 * x21 + e3 * x31;
            s2a += e0 * x02 + e1 * x12 + e2 * x22 + e3 * x32;
            da  += e0 + e1 + e2 + e3;
        }
        for (; t < cnt; t++) {
            int s = csr_src[beg + t];
            float ex = __expf(lrelu(a1s[s * 4 + h] + adh));
            s0a += ex * x[s * 3];
            s1a += ex * x[s * 3 + 1];
            s2a += ex * x[s * 3 + 2];
            da  += ex;
        }
        float4 r; r.x = s0a; r.y = s1a; r.z = s2a; r.w = da;
        *(float4*)&sm[nl][h * 4] = r;
    }
    // same-wave LDS write->read below: no barrier needed

    // ---- phase B: wave processes its own 16 nodes
    int j = lane, j2 = lane + 64;
    int h0 = j >> 5;
    float wa0 = w1[j * 3], wa1 = w1[j * 3 + 1], wa2 = w1[j * 3 + 2];
    float wb0 = w1[j2 * 3], wb1 = w1[j2 * 3 + 1], wb2 = w1[j2 * 3 + 2];
    float b1j = b1[j], b1j2 = b1[j2];
    float as2o = as2[o], ad2o = ad2[o];
    const float* f = f1s[wave];

    #pragma unroll 1
    for (int i = 0; i < 16; i++) {
        int n2 = blockIdx.x * 64 + wave * 16 + i;
        if (n2 >= N_NODES) break;
        const float* S = sm[wave * 16 + i];
        float v0 = (wa0 * S[h0 * 4] + wa1 * S[h0 * 4 + 1] + wa2 * S[h0 * 4 + 2])
                   / (S[h0 * 4 + 3] + EPS) + b1j;
        float v1 = (wb0 * S[(2 + h0) * 4] + wb1 * S[(2 + h0) * 4 + 1] + wb2 * S[(2 + h0) * 4 + 2])
                   / (S[(2 + h0) * 4 + 3] + EPS) + b1j2;
        f1s[wave][j]  = v0 > 0.f ? v0 : expm1f(v0);
        f1s[wave][j2] = v1 > 0.f ? v1 : expm1f(v1);
        float acc = 0.f;
        #pragma unroll
        for (int t = 0; t < 64; t++)
            acc += f[k0 + t] * w2r[t];
        acc += __shfl_down(acc, 32);
        if (half == 0) {
            h2[n2 * 32 + o] = acc;
            float ps = acc * as2o, pd = acc * ad2o;
            #pragma unroll
            for (int off = 16; off; off >>= 1) {
                ps += __shfl_xor(ps, off);
                pd += __shfl_xor(pd, off);
            }
            if (o == 0) { a2s[n2] = ps; a2d[n2] = pd; }
        }
    }
}

// ---------------------------------------------------------------- K-GAT2: layer-2 gather + finalize + fused u/v matvecs
#define G2_BLOCKS 4096
__global__ void k_gat2(const int* __restrict__ rowptr, const int* __restrict__ deg,
                       const int* __restrict__ csr_src,
                       const float* __restrict__ h2, const float* __restrict__ a2s,
                       const float* __restrict__ a2d, const float* __restrict__ b2,
                       const float* __restrict__ mw1, const float* __restrict__ mb1,
                       float* __restrict__ u, float* __restrict__ v) {
    int tid = threadIdx.x;
    int lane = tid & 63;
    int c = lane & 31, seg = lane >> 5;
    float A[32], B[32];
    const float4* ap = (const float4*)(mw1 + c * 64);
    #pragma unroll
    for (int q = 0; q < 8; q++) {
        float4 t = ap[q];
        A[q * 4 + 0] = t.x; A[q * 4 + 1] = t.y; A[q * 4 + 2] = t.z; A[q * 4 + 3] = t.w;
    }
    #pragma unroll
    for (int q = 0; q < 8; q++) {
        float4 t = ap[8 + q];
        B[q * 4 + 0] = t.x; B[q * 4 + 1] = t.y; B[q * 4 + 2] = t.z; B[q * 4 + 3] = t.w;
    }
    float mb1c = mb1[c], b2c = b2[c];
    int base = (blockIdx.x * 4 + (tid >> 6)) * 2 + seg;
    const int stride = G2_BLOCKS * 8;
    for (int n = base; n < N_NODES; n += stride) {
        float ad = a2d[n];
        int beg = rowptr[n], cnt = deg[n];
        float acc = 0.f, den = 0.f;
        int t = 0;
        for (; t + 4 <= cnt; t += 4) {
            int s0 = csr_src[beg + t + 0], s1 = csr_src[beg + t + 1];
            int s2 = csr_src[beg + t + 2], s3 = csr_src[beg + t + 3];
            float l0 = a2s[s0], l1 = a2s[s1], l2 = a2s[s2], l3 = a2s[s3];
            float g0 = h2[s0 * 32 + c], g1 = h2[s1 * 32 + c];
            float g2 = h2[s2 * 32 + c], g3 = h2[s3 * 32 + c];
            float e0 = __expf(lrelu(l0 + ad));
            float e1 = __expf(lrelu(l1 + ad));
            float e2 = __expf(lrelu(l2 + ad));
            float e3 = __expf(lrelu(l3 + ad));
            acc += e0 * g0 + e1 * g1 + e2 * g2 + e3 * g3;
            den += e0 + e1 + e2 + e3;
        }
        for (; t < cnt; t++) {
            int s = csr_src[beg + t];
            float ex = __expf(lrelu(a2s[s] + ad));
            acc += ex * h2[s * 32 + c];
            den += ex;
        }
        float hfc = acc / (den + EPS) + b2c;
        float uu = mb1c, vv = 0.f;
        #pragma unroll
        for (int k = 0; k < 32; k++) {
            float hk = __shfl(hfc, k, 32);
            uu += A[k] * hk;
            vv += B[k] * hk;
        }
        u[n * 32 + c] = uu;
        v[n * 32 + c] = vv;
    }
}

// ---------------------------------------------------------------- K-MLP: 8 lanes/edge, 2 edges per group per iter
#define MLP_BLOCKS 4096
__global__ void k_mlp(const int* __restrict__ ei, const float* __restrict__ u,
                      const float* __restrict__ v, const float* __restrict__ mw2,
                      const float* __restrict__ mb2, float* __restrict__ out) {
    int tid = threadIdx.x;
    int q = tid & 7;
    float4 w2q = ((const float4*)mw2)[q];
    float mb20 = mb2[0];
    int g = blockIdx.x * 32 + (tid >> 3);
    const int stride = MLP_BLOCKS * 64;
    for (int e = g * 2; e < N_EDGES; e += stride) {
        int e1ok = (e + 1 < N_EDGES);
        int src0 = ei[e], dst0 = ei[N_EDGES + e];
        int src1 = ei[e + e1ok], dst1 = ei[N_EDGES + e + e1ok];
        float4 ua0 = *(const float4*)(u + src0 * 32 + q * 4);
        float4 va0 = *(const float4*)(v + dst0 * 32 + q * 4);
        float4 ua1 = *(const float4*)(u + src1 * 32 + q * 4);
        float4 va1 = *(const float4*)(v + dst1 * 32 + q * 4);
        float s0 = fmaxf(ua0.x + va0.x, 0.f) * w2q.x
                 + fmaxf(ua0.y + va0.y, 0.f) * w2q.y
                 + fmaxf(ua0.z + va0.z, 0.f) * w2q.z
                 + fmaxf(ua0.w + va0.w, 0.f) * w2q.w;
        float s1 = fmaxf(ua1.x + va1.x, 0.f) * w2q.x
                 + fmaxf(ua1.y + va1.y, 0.f) * w2q.y
                 + fmaxf(ua1.z + va1.z, 0.f) * w2q.z
                 + fmaxf(ua1.w + va1.w, 0.f) * w2q.w;
        s0 += __shfl_xor(s0, 1, 8); s0 += __shfl_xor(s0, 2, 8); s0 += __shfl_xor(s0, 4, 8);
        s1 += __shfl_xor(s1, 1, 8); s1 += __shfl_xor(s1, 2, 8); s1 += __shfl_xor(s1, 4, 8);
        if (q == 0) {
            out[e] = fmaxf(s0 + mb20, 0.f);
            if (e1ok) out[e + 1] = fmaxf(s1 + mb20, 0.f);
        }
    }
}

// ---------------------------------------------------------------- launch
extern "C" void kernel_launch(void* const* d_in, const int* in_sizes, int n_in,
                              void* d_out, int out_size, void* d_ws, size_t ws_size,
                              hipStream_t stream) {
    const float* x    = (const float*)d_in[0];
    const int*   ei   = (const int*)d_in[1];
    const float* w1   = (const float*)d_in[2];
    const float* as1  = (const float*)d_in[3];
    const float* ad1  = (const float*)d_in[4];
    const float* b1   = (const float*)d_in[5];
    const float* w2   = (const float*)d_in[6];
    const float* as2  = (const float*)d_in[7];
    const float* ad2  = (const float*)d_in[8];
    const float* b2   = (const float*)d_in[9];
    const float* mw1  = (const float*)d_in[10];
    const float* mb1  = (const float*)d_in[11];
    const float* mw2  = (const float*)d_in[12];
    const float* mb2  = (const float*)d_in[13];
    float* out = (float*)d_out;

    const int N = N_NODES, E = N_EDGES;
    int* deg     = (int*)d_ws;           // N
    int* rowptr  = deg + N;              // N
    int* cursor  = rowptr + N;           // N
    int* loc     = cursor + N;           // N
    int* partial = loc + N;              // 512
    int* csr_src = partial + 512;        // E
    float* a1s   = (float*)(csr_src + E);// 4N
    float* a1d   = a1s + 4 * N;          // 4N
    float* h2    = a1d + 4 * N;          // 32N
    float* a2s   = h2 + 32 * N;          // N
    float* a2d   = a2s + N;              // N
    float* u     = a2d + N;              // 32N
    float* v     = u + 32 * N;           // 32N
    float* qv    = v + 32 * N;           // 24

    const int nb = (N + 255) / 256;

    k_zero_deg<<<nb, 256, 0, stream>>>(deg);
    k_hist<<<(E + 255) / 256, 256, 0, stream>>>(ei, deg);
    k_scan_part<<<nb, 256, 0, stream>>>(deg, loc, partial);
    k_scan_tot<<<1, 512, 0, stream>>>(partial, nb);
    k_scan_add<<<nb, 256, 0, stream>>>(loc, partial, rowptr, cursor);

    // range-restricted scatter passes: writes stay in a hot ~800KB L2 window
    const int step = (N + SCAT_PASSES - 1) / SCAT_PASSES;
    for (int p = 0; p < SCAT_PASSES; p++) {
        int lo = p * step;
        int hi = (lo + step < N) ? lo + step : N;
        k_scatter<<<(E + 255) / 256, 256, 0, stream>>>(ei, cursor, csr_src, lo, hi);
    }

    k_q<<<1, 32, 0, stream>>>(w1, as1, ad1, qv);
    k_node1<<<nb, 256, 0, stream>>>(x, qv, a1s, a1d);

    k_gat1<<<G1_BLOCKS, 256, 0, stream>>>(rowptr, deg, csr_src, x, w1, a1s, a1d,
                                          b1, w2, as2, ad2, h2, a2s, a2d);

    k_gat2<<<G2_BLOCKS, 256, 0, stream>>>(rowptr, deg, csr_src, h2, a2s, a2d, b2,
                                          mw1, mb1, u, v);

    k_mlp<<<MLP_BLOCKS, 256, 0, stream>>>(ei, u, v, mw2, mb2, out);
}

// Round 8
// 440.748 us; speedup vs baseline: 1.6773x; 1.1135x over previous
//
#include <hip/hip_runtime.h>
#include <math.h>

#define N_NODES 100000
#define N_EDGES 1600000
#define NEG_SLOPE 0.2f
#define EPS 1e-16f

__device__ __forceinline__ float lrelu(float v) { return v > 0.f ? v : NEG_SLOPE * v; }

// ---------------------------------------------------------------- zero deg
__global__ void k_zero_deg(int* __restrict__ deg) {
    int i = blockIdx.x * blockDim.x + threadIdx.x;
    if (i < N_NODES) deg[i] = 0;
}

// ---------------------------------------------------------------- histogram of dst
__global__ void k_hist(const int* __restrict__ ei, int* __restrict__ deg) {
    int e = blockIdx.x * blockDim.x + threadIdx.x;
    if (e < N_EDGES) atomicAdd(&deg[ei[N_EDGES + e]], 1);
}

// ---------------------------------------------------------------- scan level 1
__global__ void k_scan_part(const int* __restrict__ deg, int* __restrict__ loc,
                            int* __restrict__ partial) {
    __shared__ int tmp[256];
    int i = blockIdx.x * 256 + threadIdx.x;
    int v = (i < N_NODES) ? deg[i] : 0;
    tmp[threadIdx.x] = v;
    __syncthreads();
    for (int off = 1; off < 256; off <<= 1) {
        int t = (threadIdx.x >= off) ? tmp[threadIdx.x - off] : 0;
        __syncthreads();
        tmp[threadIdx.x] += t;
        __syncthreads();
    }
    if (i < N_NODES) loc[i] = tmp[threadIdx.x] - v;   // exclusive
    if (threadIdx.x == 255) partial[blockIdx.x] = tmp[255];
}

// ---------------------------------------------------------------- scan level 2 (nb <= 512)
__global__ void k_scan_tot(int* __restrict__ partial, int nb) {
    __shared__ int tmp[512];
    int v = (threadIdx.x < nb) ? partial[threadIdx.x] : 0;
    tmp[threadIdx.x] = v;
    __syncthreads();
    for (int off = 1; off < 512; off <<= 1) {
        int t = (threadIdx.x >= off) ? tmp[threadIdx.x - off] : 0;
        __syncthreads();
        tmp[threadIdx.x] += t;
        __syncthreads();
    }
    if (threadIdx.x < nb) partial[threadIdx.x] = tmp[threadIdx.x] - v;  // exclusive
}

// ---------------------------------------------------------------- scan level 3 + cursor init
__global__ void k_scan_add(const int* __restrict__ loc, const int* __restrict__ partial,
                           int* __restrict__ rowptr, int* __restrict__ cursor) {
    int i = blockIdx.x * blockDim.x + threadIdx.x;
    if (i < N_NODES) {
        int r = loc[i] + partial[i >> 8];
        rowptr[i] = r;
        cursor[i] = r;
    }
}

// ---------------------------------------------------------------- XCD-partitioned scatter (single launch)
// blockIdx & 7 -> XCD (round-robin heuristic). Each XCD owns 1/8 of the dst
// range: its csr window AND cursor lines are written by one XCD only, so
// atomics + writebacks stay in the local L2. dst array is read 8x (L3-hot).
#define SCATX_BLOCKS 2048
__global__ void k_scatter_x(const int* __restrict__ ei, int* __restrict__ cursor,
                            int* __restrict__ csr_src) {
    const int step = (N_NODES + 7) / 8;
    int xcd = blockIdx.x & 7;
    int lo = xcd * step;
    int hi = (lo + step < N_NODES) ? lo + step : N_NODES;
    int gid = (blockIdx.x >> 3) * blockDim.x + threadIdx.x;   // within-XCD thread id
    const int stride = (SCATX_BLOCKS >> 3) * 256;
    for (int e = gid; e < N_EDGES; e += stride) {
        int dst = ei[N_EDGES + e];
        if (dst >= lo && dst < hi) {
            int pos = atomicAdd(&cursor[dst], 1);
            csr_src[pos] = ei[e];
        }
    }
}

// ---------------------------------------------------------------- K-Q: qs[h] = W1_h^T a_src_h, qd[h] = W1_h^T a_dst_h  (24 floats)
__global__ void k_q(const float* __restrict__ w1, const float* __restrict__ as1,
                    const float* __restrict__ ad1, float* __restrict__ qv) {
    int t = threadIdx.x;
    if (t >= 24) return;
    int c = t % 3, h = (t / 3) % 4, side = t / 12;
    const float* att = side ? ad1 : as1;
    float acc = 0.f;
    for (int cc = 0; cc < 32; cc++)
        acc += att[h * 32 + cc] * w1[(h * 32 + cc) * 3 + c];
    qv[t] = acc;
}

// ---------------------------------------------------------------- K-NODE1: a1s/a1d = x . q   (1 thread/node)
__global__ void k_node1(const float* __restrict__ x, const float* __restrict__ qv,
                        float* __restrict__ a1s, float* __restrict__ a1d) {
    int n = blockIdx.x * blockDim.x + threadIdx.x;
    if (n >= N_NODES) return;
    float x0 = x[n * 3], x1 = x[n * 3 + 1], x2 = x[n * 3 + 2];
    float4 s, d;
    s.x = x0 * qv[0]  + x1 * qv[1]  + x2 * qv[2];
    s.y = x0 * qv[3]  + x1 * qv[4]  + x2 * qv[5];
    s.z = x0 * qv[6]  + x1 * qv[7]  + x2 * qv[8];
    s.w = x0 * qv[9]  + x1 * qv[10] + x2 * qv[11];
    d.x = x0 * qv[12] + x1 * qv[13] + x2 * qv[14];
    d.y = x0 * qv[15] + x1 * qv[16] + x2 * qv[17];
    d.z = x0 * qv[18] + x1 * qv[19] + x2 * qv[20];
    d.w = x0 * qv[21] + x1 * qv[22] + x2 * qv[23];
    ((float4*)a1s)[n] = s;
    ((float4*)a1d)[n] = d;
}

// ---------------------------------------------------------------- K-GAT1: linearity trick, w2 in registers
#define G1_BLOCKS ((N_NODES + 63) / 64)
__global__ void k_gat1(const int* __restrict__ rowptr, const int* __restrict__ deg,
                       const int* __restrict__ csr_src,
                       const float* __restrict__ x, const float* __restrict__ w1,
                       const float* __restrict__ a1s, const float* __restrict__ a1d,
                       const float* __restrict__ b1, const float* __restrict__ w2,
                       const float* __restrict__ as2, const float* __restrict__ ad2,
                       float* __restrict__ h2, float* __restrict__ a2s, float* __restrict__ a2d) {
    __shared__ float sm[64][16];      // per-node: 4 heads x {s0,s1,s2,den}
    __shared__ float f1s[4][128];
    int tid = threadIdx.x;
    int wave = tid >> 6, lane = tid & 63;
    int o = lane & 31, half = lane >> 5;
    int k0 = half * 64;

    // per-lane w2 column: w2[o][k0..k0+63] in 64 VGPRs
    float w2r[64];
    {
        const float4* wp = (const float4*)(w2 + o * 128 + k0);
        #pragma unroll
        for (int q = 0; q < 16; q++) {
            float4 t = wp[q];
            w2r[q * 4 + 0] = t.x; w2r[q * 4 + 1] = t.y;
            w2r[q * 4 + 2] = t.z; w2r[q * 4 + 3] = t.w;
        }
    }

    // ---- phase A: node = block*64 + wave*16 + (lane>>2), head = lane&3
    int nl = wave * 16 + (lane >> 2);
    int h  = lane & 3;
    int n  = blockIdx.x * 64 + nl;
    if (n < N_NODES) {
        float adh = a1d[n * 4 + h];
        int beg = rowptr[n], cnt = deg[n];
        float s0a = 0.f, s1a = 0.f, s2a = 0.f, da = 0.f;
        int t = 0;
        for (; t + 4 <= cnt; t += 4) {
            int s0 = csr_src[beg + t + 0], s1 = csr_src[beg + t + 1];
            int s2 = csr_src[beg + t + 2], s3 = csr_src[beg + t + 3];
            float l0 = a1s[s0 * 4 + h], l1 = a1s[s1 * 4 + h];
            float l2 = a1s[s2 * 4 + h], l3 = a1s[s3 * 4 + h];
            float x00 = x[s0 * 3], x01 = x[s0 * 3 + 1], x02 = x[s0 * 3 + 2];
            float x10 = x[s1 * 3], x11 = x[s1 * 3 + 1], x12 = x[s1 * 3 + 2];
            float x20 = x[s2 * 3], x21 = x[s2 * 3 + 1], x22 = x[s2 * 3 + 2];
            float x30 = x[s3 * 3], x31 = x[s3 * 3 + 1], x32 = x[s3 * 3 + 2];
            float e0 = __expf(lrelu(l0 + adh));
            float e1 = __expf(lrelu(l1 + adh));
            float e2 = __expf(lrelu(l2 + adh));
            float e3 = __expf(lrelu(l3 + adh));
            s0a += e0 * x00 + e1 * x10 + e2 * x20 + e3 * x30;
            s1a += e0 * x01 + e1 * x11 + e2 * x21 + e3 * x31;
            s2a += e0 * x02 + e1 * x12 + e2 * x22 + e3 * x32;
            da  += e0 + e1 + e2 + e3;
        }
        for (; t < cnt; t++) {
            int s = csr_src[beg + t];
            float ex = __expf(lrelu(a1s[s * 4 + h] + adh));
            s0a += ex * x[s * 3];
            s1a += ex * x[s * 3 + 1];
            s2a += ex * x[s * 3 + 2];
            da  += ex;
        }
        float4 r; r.x = s0a; r.y = s1a; r.z = s2a; r.w = da;
        *(float4*)&sm[nl][h * 4] = r;
    }
    // same-wave LDS write->read below: no barrier needed

    // ---- phase B: wave processes its own 16 nodes
    int j = lane, j2 = lane + 64;
    int h0 = j >> 5;
    float wa0 = w1[j * 3], wa1 = w1[j * 3 + 1], wa2 = w1[j * 3 + 2];
    float wb0 = w1[j2 * 3], wb1 = w1[j2 * 3 + 1], wb2 = w1[j2 * 3 + 2];
    float b1j = b1[j], b1j2 = b1[j2];
    float as2o = as2[o], ad2o = ad2[o];
    const float* f = f1s[wave];

    #pragma unroll 1
    for (int i = 0; i < 16; i++) {
        int n2 = blockIdx.x * 64 + wave * 16 + i;
        if (n2 >= N_NODES) break;
        const float* S = sm[wave * 16 + i];
        float v0 = (wa0 * S[h0 * 4] + wa1 * S[h0 * 4 + 1] + wa2 * S[h0 * 4 + 2])
                   / (S[h0 * 4 + 3] + EPS) + b1j;
        float v1 = (wb0 * S[(2 + h0) * 4] + wb1 * S[(2 + h0) * 4 + 1] + wb2 * S[(2 + h0) * 4 + 2])
                   / (S[(2 + h0) * 4 + 3] + EPS) + b1j2;
        f1s[wave][j]  = v0 > 0.f ? v0 : expm1f(v0);
        f1s[wave][j2] = v1 > 0.f ? v1 : expm1f(v1);
        float acc = 0.f;
        #pragma unroll
        for (int t = 0; t < 64; t++)
            acc += f[k0 + t] * w2r[t];
        acc += __shfl_down(acc, 32);
        if (half == 0) {
            h2[n2 * 32 + o] = acc;
            float ps = acc * as2o, pd = acc * ad2o;
            #pragma unroll
            for (int off = 16; off; off >>= 1) {
                ps += __shfl_xor(ps, off);
                pd += __shfl_xor(pd, off);
            }
            if (o == 0) { a2s[n2] = ps; a2d[n2] = pd; }
        }
    }
}

// ---------------------------------------------------------------- K-GAT2: full wave per node
// 64 lanes = 32 channels x 2 edge-interleaved halves; combine via shfl_xor(32);
// half 0 emits u (A-rows + mb1), half 1 emits v (B-rows).
#define G2_BLOCKS 4096
__global__ void k_gat2(const int* __restrict__ rowptr, const int* __restrict__ deg,
                       const int* __restrict__ csr_src,
                       const float* __restrict__ h2, const float* __restrict__ a2s,
                       const float* __restrict__ a2d, const float* __restrict__ b2,
                       const float* __restrict__ mw1, const float* __restrict__ mb1,
                       float* __restrict__ u, float* __restrict__ v) {
    int tid = threadIdx.x;
    int lane = tid & 63;
    int c = lane & 31, half = lane >> 5;
    float W[32];
    const float4* ap = (const float4*)(mw1 + c * 64 + half * 32);
    #pragma unroll
    for (int q = 0; q < 8; q++) {
        float4 t = ap[q];
        W[q * 4 + 0] = t.x; W[q * 4 + 1] = t.y; W[q * 4 + 2] = t.z; W[q * 4 + 3] = t.w;
    }
    float bias = half ? 0.f : mb1[c];
    float b2c = b2[c];
    float* outp = half ? v : u;
    int wid = blockIdx.x * 4 + (tid >> 6);
    const int stride = G2_BLOCKS * 4;
    for (int n = wid; n < N_NODES; n += stride) {
        float ad = a2d[n];
        int beg = rowptr[n], cnt = deg[n];
        float acc = 0.f, den = 0.f;
        // this half handles edge indices half, half+2, ... (2 per iter)
        int t = half;
        for (; t + 2 < cnt; t += 4) {
            int s0 = csr_src[beg + t], s1 = csr_src[beg + t + 2];
            float l0 = a2s[s0], l1 = a2s[s1];
            float g0 = h2[s0 * 32 + c], g1 = h2[s1 * 32 + c];
            float e0 = __expf(lrelu(l0 + ad));
            float e1 = __expf(lrelu(l1 + ad));
            acc += e0 * g0 + e1 * g1;
            den += e0 + e1;
        }
        if (t < cnt) {
            int s = csr_src[beg + t];
            float ex = __expf(lrelu(a2s[s] + ad));
            acc += ex * h2[s * 32 + c];
            den += ex;
        }
        acc += __shfl_xor(acc, 32);
        den += __shfl_xor(den, 32);
        float hfc = acc / (den + EPS) + b2c;
        float r = bias;
        #pragma unroll
        for (int k = 0; k < 32; k++)
            r += W[k] * __shfl(hfc, k, 32);
        outp[n * 32 + c] = r;
    }
}

// ---------------------------------------------------------------- K-MLP: 8 lanes/edge, 2 edges per group per iter
#define MLP_BLOCKS 4096
__global__ void k_mlp(const int* __restrict__ ei, const float* __restrict__ u,
                      const float* __restrict__ v, const float* __restrict__ mw2,
                      const float* __restrict__ mb2, float* __restrict__ out) {
    int tid = threadIdx.x;
    int q = tid & 7;
    float4 w2q = ((const float4*)mw2)[q];
    float mb20 = mb2[0];
    int g = blockIdx.x * 32 + (tid >> 3);
    const int stride = MLP_BLOCKS * 64;
    for (int e = g * 2; e < N_EDGES; e += stride) {
        int e1ok = (e + 1 < N_EDGES);
        int src0 = ei[e], dst0 = ei[N_EDGES + e];
        int src1 = ei[e + e1ok], dst1 = ei[N_EDGES + e + e1ok];
        float4 ua0 = *(const float4*)(u + src0 * 32 + q * 4);
        float4 va0 = *(const float4*)(v + dst0 * 32 + q * 4);
        float4 ua1 = *(const float4*)(u + src1 * 32 + q * 4);
        float4 va1 = *(const float4*)(v + dst1 * 32 + q * 4);
        float s0 = fmaxf(ua0.x + va0.x, 0.f) * w2q.x
                 + fmaxf(ua0.y + va0.y, 0.f) * w2q.y
                 + fmaxf(ua0.z + va0.z, 0.f) * w2q.z
                 + fmaxf(ua0.w + va0.w, 0.f) * w2q.w;
        float s1 = fmaxf(ua1.x + va1.x, 0.f) * w2q.x
                 + fmaxf(ua1.y + va1.y, 0.f) * w2q.y
                 + fmaxf(ua1.z + va1.z, 0.f) * w2q.z
                 + fmaxf(ua1.w + va1.w, 0.f) * w2q.w;
        s0 += __shfl_xor(s0, 1, 8); s0 += __shfl_xor(s0, 2, 8); s0 += __shfl_xor(s0, 4, 8);
        s1 += __shfl_xor(s1, 1, 8); s1 += __shfl_xor(s1, 2, 8); s1 += __shfl_xor(s1, 4, 8);
        if (q == 0) {
            out[e] = fmaxf(s0 + mb20, 0.f);
            if (e1ok) out[e + 1] = fmaxf(s1 + mb20, 0.f);
        }
    }
}

// ---------------------------------------------------------------- launch
extern "C" void kernel_launch(void* const* d_in, const int* in_sizes, int n_in,
                              void* d_out, int out_size, void* d_ws, size_t ws_size,
                              hipStream_t stream) {
    const float* x    = (const float*)d_in[0];
    const int*   ei   = (const int*)d_in[1];
    const float* w1   = (const float*)d_in[2];
    const float* as1  = (const float*)d_in[3];
    const float* ad1  = (const float*)d_in[4];
    const float* b1   = (const float*)d_in[5];
    const float* w2   = (const float*)d_in[6];
    const float* as2  = (const float*)d_in[7];
    const float* ad2  = (const float*)d_in[8];
    const float* b2   = (const float*)d_in[9];
    const float* mw1  = (const float*)d_in[10];
    const float* mb1  = (const float*)d_in[11];
    const float* mw2  = (const float*)d_in[12];
    const float* mb2  = (const float*)d_in[13];
    float* out = (float*)d_out;

    const int N = N_NODES, E = N_EDGES;
    int* deg     = (int*)d_ws;           // N
    int* rowptr  = deg + N;              // N
    int* cursor  = rowptr + N;           // N
    int* loc     = cursor + N;           // N
    int* partial = loc + N;              // 512
    int* csr_src = partial + 512;        // E
    float* a1s   = (float*)(csr_src + E);// 4N
    float* a1d   = a1s + 4 * N;          // 4N
    float* h2    = a1d + 4 * N;          // 32N
    float* a2s   = h2 + 32 * N;          // N
    float* a2d   = a2s + N;              // N
    float* u     = a2d + N;              // 32N
    float* v     = u + 32 * N;           // 32N
    float* qv    = v + 32 * N;           // 24

    const int nb = (N + 255) / 256;

    k_zero_deg<<<nb, 256, 0, stream>>>(deg);
    k_hist<<<(E + 255) / 256, 256, 0, stream>>>(ei, deg);
    k_scan_part<<<nb, 256, 0, stream>>>(deg, loc, partial);
    k_scan_tot<<<1, 512, 0, stream>>>(partial, nb);
    k_scan_add<<<nb, 256, 0, stream>>>(loc, partial, rowptr, cursor);

    k_scatter_x<<<SCATX_BLOCKS, 256, 0, stream>>>(ei, cursor, csr_src);

    k_q<<<1, 32, 0, stream>>>(w1, as1, ad1, qv);
    k_node1<<<nb, 256, 0, stream>>>(x, qv, a1s, a1d);

    k_gat1<<<G1_BLOCKS, 256, 0, stream>>>(rowptr, deg, csr_src, x, w1, a1s, a1d,
                                          b1, w2, as2, ad2, h2, a2s, a2d);

    k_gat2<<<G2_BLOCKS, 256, 0, stream>>>(rowptr, deg, csr_src, h2, a2s, a2d, b2,
                                          mw1, mb1, u, v);

    k_mlp<<<MLP_BLOCKS, 256, 0, stream>>>(ei, u, v, mw2, mb2, out);
}